// Round 12
// baseline (4890.141 us; speedup 1.0000x reference)
//
#include <hip/hip_runtime.h>

typedef _Float16 v8h __attribute__((ext_vector_type(8)));
typedef float v4f __attribute__((ext_vector_type(4)));
typedef unsigned int uint;

// ---- workspace layout (bytes) ----
#define OFF_BAR   0
#define OFF_AO0   4096
#define OFF_AO1   (OFF_AO0 + (1<<21))
#define OFF_AF0   (OFF_AO1 + (1<<21))
#define OFF_AF1   (OFF_AF0 + (1<<21))
#define OFF_W1    (OFF_AF1 + (1<<21))
#define OFF_W2    (OFF_W1 + (1<<21))
#define OFF_B1    (OFF_W2 + (1<<22))
#define OFF_B2    (OFF_B1 + 8192)

// Pack weights into MFMA B-fragment order:
// frag layout (16x16x32): n = nt*16 + (lane&15), k = k32*32 + (lane>>4)*8 + el
__global__ __launch_bounds__(256, 1)
void lstm_prep(const float* __restrict__ Whh1, const float* __restrict__ Wih2,
               const float* __restrict__ Whh2, const float* __restrict__ bih1,
               const float* __restrict__ bhh1, const float* __restrict__ bih2,
               const float* __restrict__ bhh2,
               _Float16* __restrict__ W1p, _Float16* __restrict__ W2p,
               float* __restrict__ bs1, float* __restrict__ bs2)
{
  const int total = 1048576 + 2097152 + 4096;
  for (int i = blockIdx.x*blockDim.x + threadIdx.x; i < total; i += gridDim.x*blockDim.x) {
    if (i < 1048576) {
      int nt = i >> 13, rem = i & 8191;
      int k32 = rem >> 9, c = rem & 511;
      int lane = c >> 3, el = c & 7;
      int n = nt*16 + (lane & 15);
      int k = k32*32 + (lane >> 4)*8 + el;
      W1p[i] = (_Float16)Whh1[n*512 + k];
    } else if (i < 3145728) {
      int j = i - 1048576;
      int nt = j >> 14, rem = j & 16383;
      int k32 = rem >> 9, c = rem & 511;
      int lane = c >> 3, el = c & 7;
      int n = nt*16 + (lane & 15);
      int k = k32*32 + (lane >> 4)*8 + el;
      float v = (k < 512) ? Wih2[n*512 + k] : Whh2[n*512 + (k - 512)];
      W2p[j] = (_Float16)v;
    } else {
      int n = i - 3145728;
      if (n < 2048) bs1[n] = bih1[n] + bhh1[n];
      else          bs2[n-2048] = bih2[n-2048] + bhh2[n-2048];
    }
  }
}

__device__ __forceinline__ float sigmoidf_(float z) { return 1.f / (1.f + __expf(-z)); }
__device__ __forceinline__ float tanhf_(float z)    { return 1.f - 2.f/(1.f + __expf(2.f*z)); }

// agent-scope relaxed 16B fragment load (2x8B): proven-correct exchange primitive
__device__ __forceinline__ v8h ld_frag_dev(const _Float16* base, uint off) {
  union { unsigned long long u[2]; v8h h; } cv;
  const unsigned long long* q = (const unsigned long long*)(base + off);
  cv.u[0] = __hip_atomic_load(q,     __ATOMIC_RELAXED, __HIP_MEMORY_SCOPE_AGENT);
  cv.u[1] = __hip_atomic_load(q + 1, __ATOMIC_RELAXED, __HIP_MEMORY_SCOPE_AGENT);
  return cv.h;
}

// R18 = R16/R9 base (confirmed 2916us) + ONE structural simplification:
// NO K-SPLIT. Wave = cell(2) x mtile(2) instead of cell x K-half. Per-wave
// MFMA count, acc footprint (64 VGPR), and A-load count are UNCHANGED; each
// wave owns one 16-row mtile across the FULL K. The LDS dump+combine
// (32KB round-trip + 2 syncs on the GEMM->epilogue critical path, every
// round) is deleted: 8 syncs -> 6. Bit-exactness preserved by accumulating
// the two K-halves in separate acc0/acc1 MFMA chains and adding at the end
// (reproduces kh0-chain + kh1-chain + combine order exactly).
// Cost: cell2 waves issue 2x B-loads (L2-resident; issue pressure only).
// R17 lesson: co-resident-block overlap is saturated (stagger neutral); only
// shortening the per-block serial chain can help.
// LDS: gred 32x132 at [0,4224); stash 32x36 fp32 at [8448,9600);
// 56KB declared to force <=2 blocks/CU co-residency (unchanged).
__global__ __launch_bounds__(256, 2)
void lstm_main(const float* __restrict__ x, const float* __restrict__ Wih1,
               const float* __restrict__ Wl, const float* __restrict__ blv,
               _Float16* __restrict__ AO0, _Float16* __restrict__ AO1,
               _Float16* __restrict__ AF0, _Float16* __restrict__ AF1,
               const _Float16* __restrict__ W1, const _Float16* __restrict__ W2,
               const float* __restrict__ bs1, const float* __restrict__ bs2,
               int* __restrict__ bar, float* __restrict__ out)
{
  __shared__ float lred[14336];        // 56KB: forces <=2 blocks/CU
  const int tid  = threadIdx.x;
  const int wv   = tid >> 6, lane = tid & 63;
  const int quad = lane >> 4, lc = lane & 15;
  const int cw   = wv & 1;           // cell
  const int mtb  = wv >> 1;          // mtile within block (16 rows each)
  const int bid  = blockIdx.x;
  const int jg   = bid >> 3;
  const int ht   = (bid & 7)*2 + (jg & 1);   // XCD swizzle, 0..15
  const int bt   = jg >> 1;                  // 0..31 (32 rows each)

  _Float16* const AOv[2] = {AO0, AO1};
  _Float16* const AFv[2] = {AF0, AF1};

  // epilogue-compute ownership (all 256): row erow (0..31), cols enib*4..+3
  const int erow = tid >> 3, enib = tid & 7;
  // store ownership (tid>=128): tid2 -> (b_loc, oct)
  const int tid2  = tid - 128;
  const int b_loc = (tid2 >= 0) ? (tid2 >> 2) : 0, oct = tid2 & 3;
  const int m     = b_loc & 15, mtile_e = bt*2 + (b_loc >> 4);
  const int STASH = 8448;

  int ntg_[8];
  #pragma unroll
  for (int tt = 0; tt < 8; tt++) ntg_[tt] = (tt>>1)*32 + ht*2 + (tt&1);

  float c1s[4], c2s[4];
  #pragma unroll
  for (int i = 0; i < 4; i++) { c1s[i] = 0.f; c2s[i] = 0.f; }

  for (int r = 0; r < 162; r++) {
    const bool p1 = r < 129;
    const int  f  = r - 129;
    const int  wp = p1 ? (r & 1) : (f & 1);   // write parity
    const int  rp = wp ^ 1;                   // read parity
    const _Float16* A1 = p1 ? AOv[rp] : AFv[rp];
    const _Float16* A2 = AOv[rp];
    const bool skip1 = (r == 128 || r == 161);
    const bool skip2 = (r == 0   || r == 129);

    // ---- this wave's GEMM: one mtile, FULL K, two bit-exact half-chains ----
    const _Float16* Ac = cw ? A2 : A1;
    const _Float16* Bc = cw ? W2 : (p1 ? W1 : W2);
    const int HF = cw ? 32 : (p1 ? 16 : 32);  // K in 32-wide chunks (= wk)
    const int HH = HF >> 1;

    v4f acc0[8], acc1[8];
    #pragma unroll
    for (int tt = 0; tt < 8; tt++) { acc0[tt] = (v4f){0,0,0,0}; acc1[tt] = (v4f){0,0,0,0}; }

    const uint aoff = (uint)(((bt*2 + mtb)*32)*512 + lane*8);
    uint boff[8];
    #pragma unroll
    for (int tt = 0; tt < 8; tt++)
      boff[tt] = (uint)((ntg_[tt]*HF)*512 + lane*8);

    #pragma unroll 4
    for (int cc = 0; cc < HH; cc++) {           // K-half 0 (== old kh0 chain)
      v8h av = ld_frag_dev(Ac, aoff + cc*512);
      #pragma unroll
      for (int tt = 0; tt < 8; tt++) {
        v8h bv = *(const v8h*)(Bc + boff[tt] + cc*512);
        acc0[tt] = __builtin_amdgcn_mfma_f32_16x16x32_f16(av, bv, acc0[tt], 0, 0, 0);
      }
    }
    #pragma unroll 4
    for (int cc = HH; cc < 2*HH; cc++) {        // K-half 1 (== old kh1 chain)
      v8h av = ld_frag_dev(Ac, aoff + cc*512);
      #pragma unroll
      for (int tt = 0; tt < 8; tt++) {
        v8h bv = *(const v8h*)(Bc + boff[tt] + cc*512);
        acc1[tt] = __builtin_amdgcn_mfma_f32_16x16x32_f16(av, bv, acc1[tt], 0, 0, 0);
      }
    }
    #pragma unroll
    for (int tt = 0; tt < 8; tt++) acc0[tt] += acc1[tt];  // == old kh0 + kh1 combine

    // ---- scatter cell1 into gred (stride 132) by cell1 waves (wv0, wv2) ----
    if (cw == 0) {
      #pragma unroll
      for (int tt = 0; tt < 8; tt++) {
        int row = mtb*16 + quad*4;
        int col = tt*16 + lc;
        #pragma unroll
        for (int rr = 0; rr < 4; rr++) lred[(row + rr)*132 + col] = acc0[tt][rr];
      }
    }
    __syncthreads();

    // ================= epilogue cell1 (all 256 threads) =================
    {
      const float* bsx = p1 ? bs1 : bs2;
      float g[4][4];
      #pragma unroll
      for (int g4 = 0; g4 < 4; g4++) {
        v4f gv = *(const v4f*)&lred[erow*132 + g4*32 + enib*4];
        v4f bv = *(const v4f*)&bsx[g4*512 + ht*32 + enib*4];
        #pragma unroll
        for (int j = 0; j < 4; j++) g[g4][j] = gv[j] + bv[j];
      }
      if (p1 && r < 128) {             // + x @ Wih1^T (K=4, exact fp32)
        const v4f xv = *(const v4f*)(x + ((size_t)r*1024 + bt*32 + erow)*4);
        #pragma unroll
        for (int g4 = 0; g4 < 4; g4++)
          #pragma unroll
          for (int j = 0; j < 4; j++) {
            int hh = ht*32 + enib*4 + j;
            const v4f w = *(const v4f*)(Wih1 + (size_t)(g4*512 + hh)*4);
            g[g4][j] += xv[0]*w[0] + xv[1]*w[1] + xv[2]*w[2] + xv[3]*w[3];
          }
      }
      if (!skip1) {
        v4f hf;
        #pragma unroll
        for (int j = 0; j < 4; j++) {
          float ig = sigmoidf_(g[0][j]), fg = sigmoidf_(g[1][j]);
          float gg = tanhf_(g[2][j]),    og = sigmoidf_(g[3][j]);
          float c = fg*c1s[j] + ig*gg;
          c1s[j] = c;
          hf[j] = og * tanhf_(c);
        }
        *(v4f*)&lred[STASH + erow*36 + enib*4] = hf;
      }
    }
    __syncthreads();

    // ---- concurrent: store h1 (tid>=128, from stash) + scatter cell2 (wv1,wv3) ----
    if (tid >= 128 && !skip1) {
      v4f h0 = *(const v4f*)&lred[STASH + b_loc*36 + oct*8];
      v4f h1 = *(const v4f*)&lred[STASH + b_loc*36 + oct*8 + 4];
      union { _Float16 h8[8]; unsigned long long u[2]; } hu;
      #pragma unroll
      for (int j = 0; j < 4; j++) { hu.h8[j] = (_Float16)h0[j]; hu.h8[4+j] = (_Float16)h1[j]; }
      auto st16 = [&](_Float16* bp, int chunk) {
        unsigned long long* p = (unsigned long long*)
          (bp + (((size_t)(mtile_e*32 + chunk)) << 9) + (oct*16 + m)*8);
        __hip_atomic_store(p,     hu.u[0], __ATOMIC_RELAXED, __HIP_MEMORY_SCOPE_AGENT);
        __hip_atomic_store(p + 1, hu.u[1], __ATOMIC_RELAXED, __HIP_MEMORY_SCOPE_AGENT);
      };
      if (p1) {
        st16(AOv[wp], ht);
        if (r == 127) st16(AFv[1], 16 + ht);   // h1(127) for f=0's h1f-GEMM
      } else {
        st16(AFv[wp], 16 + ht);
        st16(AOv[wp], ht);
      }
    }
    if (cw == 1) {                     // scatter cell2 into gred (waves wv1, wv3)
      #pragma unroll
      for (int tt = 0; tt < 8; tt++) {
        int row = mtb*16 + quad*4;
        int col = tt*16 + lc;
        #pragma unroll
        for (int rr = 0; rr < 4; rr++) lred[(row + rr)*132 + col] = acc0[tt][rr];
      }
    }
    __syncthreads();

    // ================= epilogue cell2 (all 256 threads) =================
    {
      float g[4][4];
      #pragma unroll
      for (int g4 = 0; g4 < 4; g4++) {
        v4f gv = *(const v4f*)&lred[erow*132 + g4*32 + enib*4];
        v4f bv = *(const v4f*)&bs2[g4*512 + ht*32 + enib*4];
        #pragma unroll
        for (int j = 0; j < 4; j++) g[g4][j] = gv[j] + bv[j];
      }
      if (!skip2) {
        v4f hf;
        #pragma unroll
        for (int j = 0; j < 4; j++) {
          float ig = sigmoidf_(g[0][j]), fg = sigmoidf_(g[1][j]);
          float gg = tanhf_(g[2][j]),    og = sigmoidf_(g[3][j]);
          float c = fg*c2s[j] + ig*gg;
          c2s[j] = c;
          hf[j] = og * tanhf_(c);
        }
        *(v4f*)&lred[STASH + erow*36 + enib*4] = hf;
      }
    }
    __syncthreads();

    // ---- store h2 (tid>=128) + out-projection (tid<128, phase2) ----
    if (tid >= 128 && !skip2) {
      v4f h0 = *(const v4f*)&lred[STASH + b_loc*36 + oct*8];
      v4f h1 = *(const v4f*)&lred[STASH + b_loc*36 + oct*8 + 4];
      union { _Float16 h8[8]; unsigned long long u[2]; } hu;
      #pragma unroll
      for (int j = 0; j < 4; j++) { hu.h8[j] = (_Float16)h0[j]; hu.h8[4+j] = (_Float16)h1[j]; }
      auto st16 = [&](_Float16* bp, int chunk) {
        unsigned long long* p = (unsigned long long*)
          (bp + (((size_t)(mtile_e*32 + chunk)) << 9) + (oct*16 + m)*8);
        __hip_atomic_store(p,     hu.u[0], __ATOMIC_RELAXED, __HIP_MEMORY_SCOPE_AGENT);
        __hip_atomic_store(p + 1, hu.u[1], __ATOMIC_RELAXED, __HIP_MEMORY_SCOPE_AGENT);
      };
      st16(AOv[wp], 16 + ht);
      if (r == 128) { st16(AFv[0], ht); st16(AFv[1], ht); }   // tmp = h2(127)
    }
    if (tid < 128 && !p1 && r >= 130) {  // out(s) = h2f(s) @ Wl^T + bl, s = r-130
      const int s = r - 130;
      int bb = tid >> 2, o = tid & 3;
      float sa = (ht == 0) ? blv[o] : 0.f;
      const float* wl = Wl + (size_t)o*512 + ht*32;
      #pragma unroll
      for (int jj = 0; jj < 32; jj++) sa += lred[STASH + bb*36 + jj] * wl[jj];
      atomicAdd(&out[(((size_t)s*1024) + bt*32 + bb)*4 + o], sa);
    }
    __syncthreads();

    // ---- per-bt-group barrier: agent-relaxed add + relaxed poll ----
    if (tid == 0) {
      int* ctr = bar + bt*32;          // 128B-spaced counters, 32 groups
      __hip_atomic_fetch_add(ctr, 1, __ATOMIC_RELAXED, __HIP_MEMORY_SCOPE_AGENT);
      const int target = 16*(r+1);
      while (__hip_atomic_load(ctr, __ATOMIC_RELAXED, __HIP_MEMORY_SCOPE_AGENT) < target)
        __builtin_amdgcn_s_sleep(1);
    }
    __syncthreads();
  }
}

extern "C" void kernel_launch(void* const* d_in, const int* in_sizes, int n_in,
                              void* d_out, int out_size, void* d_ws, size_t ws_size,
                              hipStream_t stream) {
  const float* x    = (const float*)d_in[0];
  const float* Wih1 = (const float*)d_in[1];
  const float* Whh1 = (const float*)d_in[2];
  const float* bih1 = (const float*)d_in[3];
  const float* bhh1 = (const float*)d_in[4];
  const float* Wih2 = (const float*)d_in[5];
  const float* Whh2 = (const float*)d_in[6];
  const float* bih2 = (const float*)d_in[7];
  const float* bhh2 = (const float*)d_in[8];
  const float* Wl   = (const float*)d_in[9];
  const float* bl   = (const float*)d_in[10];

  char* ws = (char*)d_ws;
  int*      bar = (int*)(ws + OFF_BAR);
  _Float16* AO0 = (_Float16*)(ws + OFF_AO0);
  _Float16* AO1 = (_Float16*)(ws + OFF_AO1);
  _Float16* AF0 = (_Float16*)(ws + OFF_AF0);
  _Float16* AF1 = (_Float16*)(ws + OFF_AF1);
  _Float16* W1p = (_Float16*)(ws + OFF_W1);
  _Float16* W2p = (_Float16*)(ws + OFF_W2);
  float*    bs1 = (float*)(ws + OFF_B1);
  float*    bs2 = (float*)(ws + OFF_B2);

  // zero barrier + state buffers (h,c start at 0); zero out (atomic accumulation)
  hipMemsetAsync(ws, 0, (size_t)OFF_W1, stream);
  hipMemsetAsync(d_out, 0, (size_t)out_size * sizeof(float), stream);

  lstm_prep<<<2048, 256, 0, stream>>>(Whh1, Wih2, Whh2, bih1, bhh1, bih2, bhh2,
                                      W1p, W2p, bs1, bs2);
  lstm_main<<<512, 256, 0, stream>>>(x, Wih1, Wl, bl, AO0, AO1, AF0, AF1,
                                     W1p, W2p, bs1, bs2, bar, (float*)d_out);
}

// Round 13
// 2891.378 us; speedup vs baseline: 1.6913x; 1.6913x over previous
//
#include <hip/hip_runtime.h>

typedef _Float16 v8h __attribute__((ext_vector_type(8)));
typedef float v4f __attribute__((ext_vector_type(4)));
typedef unsigned int uint;

// ---- workspace layout (bytes) ----
#define OFF_BAR   0
#define OFF_AO0   4096
#define OFF_AO1   (OFF_AO0 + (1<<21))
#define OFF_AF0   (OFF_AO1 + (1<<21))
#define OFF_AF1   (OFF_AF0 + (1<<21))
#define OFF_W1    (OFF_AF1 + (1<<21))
#define OFF_W2    (OFF_W1 + (1<<21))
#define OFF_B1    (OFF_W2 + (1<<22))
#define OFF_B2    (OFF_B1 + 8192)

// Pack weights into MFMA B-fragment order:
// frag layout (16x16x32): n = nt*16 + (lane&15), k = k32*32 + (lane>>4)*8 + el
__global__ __launch_bounds__(256, 1)
void lstm_prep(const float* __restrict__ Whh1, const float* __restrict__ Wih2,
               const float* __restrict__ Whh2, const float* __restrict__ bih1,
               const float* __restrict__ bhh1, const float* __restrict__ bih2,
               const float* __restrict__ bhh2,
               _Float16* __restrict__ W1p, _Float16* __restrict__ W2p,
               float* __restrict__ bs1, float* __restrict__ bs2)
{
  const int total = 1048576 + 2097152 + 4096;
  for (int i = blockIdx.x*blockDim.x + threadIdx.x; i < total; i += gridDim.x*blockDim.x) {
    if (i < 1048576) {
      int nt = i >> 13, rem = i & 8191;
      int k32 = rem >> 9, c = rem & 511;
      int lane = c >> 3, el = c & 7;
      int n = nt*16 + (lane & 15);
      int k = k32*32 + (lane >> 4)*8 + el;
      W1p[i] = (_Float16)Whh1[n*512 + k];
    } else if (i < 3145728) {
      int j = i - 1048576;
      int nt = j >> 14, rem = j & 16383;
      int k32 = rem >> 9, c = rem & 511;
      int lane = c >> 3, el = c & 7;
      int n = nt*16 + (lane & 15);
      int k = k32*32 + (lane >> 4)*8 + el;
      float v = (k < 512) ? Wih2[n*512 + k] : Whh2[n*512 + (k - 512)];
      W2p[j] = (_Float16)v;
    } else {
      int n = i - 3145728;
      if (n < 2048) bs1[n] = bih1[n] + bhh1[n];
      else          bs2[n-2048] = bih2[n-2048] + bhh2[n-2048];
    }
  }
}

__device__ __forceinline__ float sigmoidf_(float z) { return 1.f / (1.f + __expf(-z)); }
__device__ __forceinline__ float tanhf_(float z)    { return 1.f - 2.f/(1.f + __expf(2.f*z)); }

// agent-scope relaxed 16B fragment load (2x8B): proven-correct exchange primitive
__device__ __forceinline__ v8h ld_frag_dev(const _Float16* base, uint off) {
  union { unsigned long long u[2]; v8h h; } cv;
  const unsigned long long* q = (const unsigned long long*)(base + off);
  cv.u[0] = __hip_atomic_load(q,     __ATOMIC_RELAXED, __HIP_MEMORY_SCOPE_AGENT);
  cv.u[1] = __hip_atomic_load(q + 1, __ATOMIC_RELAXED, __HIP_MEMORY_SCOPE_AGENT);
  return cv.h;
}

// FINAL = R9/R16 VERBATIM — the session's best verified kernel (2915.7us,
// reproduced twice). Full exploration record (vs this base):
//  R9  512x256, 2 independent barrier domains/CU ............ -6%  WIN (this)
//  R7  concentrate epilogue on GEMM waves ................... +100% FAIL
//  R8  SIMD MFMA balance (cw^kh) ............................ neutral
//  R10 manual 8-deep A-load pipeline ........................ +24% FAIL
//  R12 5-sync phase merge ................................... +6%  FAIL
//  R13 dataflow flags replacing global barrier .............. +7%  FAIL
//  R14 2x occupancy (4 blocks/CU, 16-col tiles) ............. +63% FAIL
//  R15 operand hoisting (bias/Wih1 to regs) ................. +65% FAIL
//  R17 anti-phase startup stagger ........................... neutral
//  R18 K-split removal (full-K per wave) .................... +68% FAIL
// Key structural facts encoded by those results:
//  (a) the kh-split IS wave-parallelism over K — two waves run the two
//      K-halves concurrently; removing it doubles the GEMM critical path;
//  (b) the GEMM inner loop depends on compiler scheduling freedom — adding
//      live registers or manual pipelining breaks it;
//  (c) occupancy is not the limiter (all pipes <25%); co-resident-block
//      overlap is saturated (stagger neutral);
//  (d) the round is bound by the cross-block h-exchange RTT + phase chain —
//      a latency floor, not a BW/compute roofline (HBM 10%, MFMA 16%).
// Waves: kh=wv>>1 (K half), cw=(wv&1)^kh (cell; each SIMD-pair balanced).
// LDS: dump regions cw*4096 floats [0,8192); gred 32x132 at [0,4224);
// stash 32x36 fp32 at [8448,9600); 56KB forces <=2 blocks/CU co-residency.
__global__ __launch_bounds__(256, 2)
void lstm_main(const float* __restrict__ x, const float* __restrict__ Wih1,
               const float* __restrict__ Wl, const float* __restrict__ blv,
               _Float16* __restrict__ AO0, _Float16* __restrict__ AO1,
               _Float16* __restrict__ AF0, _Float16* __restrict__ AF1,
               const _Float16* __restrict__ W1, const _Float16* __restrict__ W2,
               const float* __restrict__ bs1, const float* __restrict__ bs2,
               int* __restrict__ bar, float* __restrict__ out)
{
  __shared__ float lred[14336];        // 56KB: forces <=2 blocks/CU
  const int tid  = threadIdx.x;
  const int wv   = tid >> 6, lane = tid & 63;
  const int quad = lane >> 4, lc = lane & 15;
  const int kh   = wv >> 1;          // K half
  const int cw   = (wv & 1) ^ kh;    // cell
  const int bid  = blockIdx.x;
  const int jg   = bid >> 3;
  const int ht   = (bid & 7)*2 + (jg & 1);   // XCD swizzle, 0..15
  const int bt   = jg >> 1;                  // 0..31 (32 rows each)

  _Float16* const AOv[2] = {AO0, AO1};
  _Float16* const AFv[2] = {AF0, AF1};

  // epilogue-compute ownership (all 256): row erow (0..31), cols enib*4..+3
  const int erow = tid >> 3, enib = tid & 7;
  // store ownership (tid>=128): tid2 -> (b_loc, oct)
  const int tid2  = tid - 128;
  const int b_loc = (tid2 >= 0) ? (tid2 >> 2) : 0, oct = tid2 & 3;
  const int m     = b_loc & 15, mtile_e = bt*2 + (b_loc >> 4);
  const int STASH = 8448;

  int ntg_[8];
  #pragma unroll
  for (int tt = 0; tt < 8; tt++) ntg_[tt] = (tt>>1)*32 + ht*2 + (tt&1);

  float c1s[4], c2s[4];
  #pragma unroll
  for (int i = 0; i < 4; i++) { c1s[i] = 0.f; c2s[i] = 0.f; }

  for (int r = 0; r < 162; r++) {
    const bool p1 = r < 129;
    const int  f  = r - 129;
    const int  wp = p1 ? (r & 1) : (f & 1);   // write parity
    const int  rp = wp ^ 1;                   // read parity
    const _Float16* A1 = p1 ? AOv[rp] : AFv[rp];
    const _Float16* A2 = AOv[rp];
    const bool skip1 = (r == 128 || r == 161);
    const bool skip2 = (r == 0   || r == 129);

    // ---- this wave's GEMM ----
    const _Float16* Ac = cw ? A2 : A1;
    const _Float16* Bc = cw ? W2 : (p1 ? W1 : W2);
    const int wk   = cw ? 32 : (p1 ? 16 : 32);
    const int half = cw ? 16 : (p1 ? 8 : 16);
    const int ch0  = kh * half;

    v4f acc[2][8];
    #pragma unroll
    for (int i2 = 0; i2 < 2; i2++)
      #pragma unroll
      for (int tt = 0; tt < 8; tt++) acc[i2][tt] = (v4f){0,0,0,0};

    uint aoff[2];
    #pragma unroll
    for (int i2 = 0; i2 < 2; i2++)
      aoff[i2] = (uint)(((bt*2 + i2)*32 + ch0)*512 + lane*8);
    uint boff[8];
    #pragma unroll
    for (int tt = 0; tt < 8; tt++)
      boff[tt] = (uint)((ntg_[tt]*wk + ch0)*512 + lane*8);

    #pragma unroll 4
    for (int cc = 0; cc < half; cc++) {
      v8h av[2];
      #pragma unroll
      for (int i2 = 0; i2 < 2; i2++)
        av[i2] = ld_frag_dev(Ac, aoff[i2] + cc*512);
      #pragma unroll
      for (int tt = 0; tt < 8; tt++) {
        v8h bv = *(const v8h*)(Bc + boff[tt] + cc*512);
        #pragma unroll
        for (int i2 = 0; i2 < 2; i2++)
          acc[i2][tt] = __builtin_amdgcn_mfma_f32_16x16x32_f16(av[i2], bv, acc[i2][tt], 0, 0, 0);
      }
    }

    // ---- K-reduce: kh=1 waves dump, kh=0 waves combine ----
    const int rbase = cw * 4096;
    if (kh) {
      #pragma unroll
      for (int i2 = 0; i2 < 2; i2++)
        #pragma unroll
        for (int tt = 0; tt < 8; tt++)
          *(v4f*)&lred[rbase + ((i2*8 + tt)*64 + lane)*4] = acc[i2][tt];
    }
    __syncthreads();
    if (!kh) {
      #pragma unroll
      for (int i2 = 0; i2 < 2; i2++)
        #pragma unroll
        for (int tt = 0; tt < 8; tt++)
          acc[i2][tt] += *(const v4f*)&lred[rbase + ((i2*8 + tt)*64 + lane)*4];
    }
    __syncthreads();

    // ---- scatter cell1 into gred (stride 132) by wave wv0 ----
    if (!kh && cw == 0) {
      #pragma unroll
      for (int i2 = 0; i2 < 2; i2++)
        #pragma unroll
        for (int tt = 0; tt < 8; tt++) {
          int row = i2*16 + quad*4;
          int col = tt*16 + lc;
          #pragma unroll
          for (int rr = 0; rr < 4; rr++) lred[(row + rr)*132 + col] = acc[i2][tt][rr];
        }
    }
    __syncthreads();

    // ================= epilogue cell1 (all 256 threads) =================
    {
      const float* bsx = p1 ? bs1 : bs2;
      float g[4][4];
      #pragma unroll
      for (int g4 = 0; g4 < 4; g4++) {
        v4f gv = *(const v4f*)&lred[erow*132 + g4*32 + enib*4];
        v4f bv = *(const v4f*)&bsx[g4*512 + ht*32 + enib*4];
        #pragma unroll
        for (int j = 0; j < 4; j++) g[g4][j] = gv[j] + bv[j];
      }
      if (p1 && r < 128) {             // + x @ Wih1^T (K=4, exact fp32)
        const v4f xv = *(const v4f*)(x + ((size_t)r*1024 + bt*32 + erow)*4);
        #pragma unroll
        for (int g4 = 0; g4 < 4; g4++)
          #pragma unroll
          for (int j = 0; j < 4; j++) {
            int hh = ht*32 + enib*4 + j;
            const v4f w = *(const v4f*)(Wih1 + (size_t)(g4*512 + hh)*4);
            g[g4][j] += xv[0]*w[0] + xv[1]*w[1] + xv[2]*w[2] + xv[3]*w[3];
          }
      }
      if (!skip1) {
        v4f hf;
        #pragma unroll
        for (int j = 0; j < 4; j++) {
          float ig = sigmoidf_(g[0][j]), fg = sigmoidf_(g[1][j]);
          float gg = tanhf_(g[2][j]),    og = sigmoidf_(g[3][j]);
          float c = fg*c1s[j] + ig*gg;
          c1s[j] = c;
          hf[j] = og * tanhf_(c);
        }
        *(v4f*)&lred[STASH + erow*36 + enib*4] = hf;
      }
    }
    __syncthreads();

    // ---- concurrent: store h1 (tid>=128, from stash) + scatter cell2 (wv1) ----
    if (tid >= 128 && !skip1) {
      v4f h0 = *(const v4f*)&lred[STASH + b_loc*36 + oct*8];
      v4f h1 = *(const v4f*)&lred[STASH + b_loc*36 + oct*8 + 4];
      union { _Float16 h8[8]; unsigned long long u[2]; } hu;
      #pragma unroll
      for (int j = 0; j < 4; j++) { hu.h8[j] = (_Float16)h0[j]; hu.h8[4+j] = (_Float16)h1[j]; }
      auto st16 = [&](_Float16* bp, int chunk) {
        unsigned long long* p = (unsigned long long*)
          (bp + (((size_t)(mtile_e*32 + chunk)) << 9) + (oct*16 + m)*8);
        __hip_atomic_store(p,     hu.u[0], __ATOMIC_RELAXED, __HIP_MEMORY_SCOPE_AGENT);
        __hip_atomic_store(p + 1, hu.u[1], __ATOMIC_RELAXED, __HIP_MEMORY_SCOPE_AGENT);
      };
      if (p1) {
        st16(AOv[wp], ht);
        if (r == 127) st16(AFv[1], 16 + ht);   // h1(127) for f=0's h1f-GEMM
      } else {
        st16(AFv[wp], 16 + ht);
        st16(AOv[wp], ht);
      }
    }
    if (!kh && cw == 1) {              // scatter cell2 into gred (wave wv1)
      #pragma unroll
      for (int i2 = 0; i2 < 2; i2++)
        #pragma unroll
        for (int tt = 0; tt < 8; tt++) {
          int row = i2*16 + quad*4;
          int col = tt*16 + lc;
          #pragma unroll
          for (int rr = 0; rr < 4; rr++) lred[(row + rr)*132 + col] = acc[i2][tt][rr];
        }
    }
    __syncthreads();

    // ================= epilogue cell2 (all 256 threads) =================
    {
      float g[4][4];
      #pragma unroll
      for (int g4 = 0; g4 < 4; g4++) {
        v4f gv = *(const v4f*)&lred[erow*132 + g4*32 + enib*4];
        v4f bv = *(const v4f*)&bs2[g4*512 + ht*32 + enib*4];
        #pragma unroll
        for (int j = 0; j < 4; j++) g[g4][j] = gv[j] + bv[j];
      }
      if (!skip2) {
        v4f hf;
        #pragma unroll
        for (int j = 0; j < 4; j++) {
          float ig = sigmoidf_(g[0][j]), fg = sigmoidf_(g[1][j]);
          float gg = tanhf_(g[2][j]),    og = sigmoidf_(g[3][j]);
          float c = fg*c2s[j] + ig*gg;
          c2s[j] = c;
          hf[j] = og * tanhf_(c);
        }
        *(v4f*)&lred[STASH + erow*36 + enib*4] = hf;
      }
    }
    __syncthreads();

    // ---- store h2 (tid>=128) + out-projection (tid<128, phase2) ----
    if (tid >= 128 && !skip2) {
      v4f h0 = *(const v4f*)&lred[STASH + b_loc*36 + oct*8];
      v4f h1 = *(const v4f*)&lred[STASH + b_loc*36 + oct*8 + 4];
      union { _Float16 h8[8]; unsigned long long u[2]; } hu;
      #pragma unroll
      for (int j = 0; j < 4; j++) { hu.h8[j] = (_Float16)h0[j]; hu.h8[4+j] = (_Float16)h1[j]; }
      auto st16 = [&](_Float16* bp, int chunk) {
        unsigned long long* p = (unsigned long long*)
          (bp + (((size_t)(mtile_e*32 + chunk)) << 9) + (oct*16 + m)*8);
        __hip_atomic_store(p,     hu.u[0], __ATOMIC_RELAXED, __HIP_MEMORY_SCOPE_AGENT);
        __hip_atomic_store(p + 1, hu.u[1], __ATOMIC_RELAXED, __HIP_MEMORY_SCOPE_AGENT);
      };
      st16(AOv[wp], 16 + ht);
      if (r == 128) { st16(AFv[0], ht); st16(AFv[1], ht); }   // tmp = h2(127)
    }
    if (tid < 128 && !p1 && r >= 130) {  // out(s) = h2f(s) @ Wl^T + bl, s = r-130
      const int s = r - 130;
      int bb = tid >> 2, o = tid & 3;
      float sa = (ht == 0) ? blv[o] : 0.f;
      const float* wl = Wl + (size_t)o*512 + ht*32;
      #pragma unroll
      for (int jj = 0; jj < 32; jj++) sa += lred[STASH + bb*36 + jj] * wl[jj];
      atomicAdd(&out[(((size_t)s*1024) + bt*32 + bb)*4 + o], sa);
    }
    __syncthreads();

    // ---- per-bt-group barrier: agent-relaxed add + relaxed poll ----
    if (tid == 0) {
      int* ctr = bar + bt*32;          // 128B-spaced counters, 32 groups
      __hip_atomic_fetch_add(ctr, 1, __ATOMIC_RELAXED, __HIP_MEMORY_SCOPE_AGENT);
      const int target = 16*(r+1);
      while (__hip_atomic_load(ctr, __ATOMIC_RELAXED, __HIP_MEMORY_SCOPE_AGENT) < target)
        __builtin_amdgcn_s_sleep(1);
    }
    __syncthreads();
  }
}

extern "C" void kernel_launch(void* const* d_in, const int* in_sizes, int n_in,
                              void* d_out, int out_size, void* d_ws, size_t ws_size,
                              hipStream_t stream) {
  const float* x    = (const float*)d_in[0];
  const float* Wih1 = (const float*)d_in[1];
  const float* Whh1 = (const float*)d_in[2];
  const float* bih1 = (const float*)d_in[3];
  const float* bhh1 = (const float*)d_in[4];
  const float* Wih2 = (const float*)d_in[5];
  const float* Whh2 = (const float*)d_in[6];
  const float* bih2 = (const float*)d_in[7];
  const float* bhh2 = (const float*)d_in[8];
  const float* Wl   = (const float*)d_in[9];
  const float* bl   = (const float*)d_in[10];

  char* ws = (char*)d_ws;
  int*      bar = (int*)(ws + OFF_BAR);
  _Float16* AO0 = (_Float16*)(ws + OFF_AO0);
  _Float16* AO1 = (_Float16*)(ws + OFF_AO1);
  _Float16* AF0 = (_Float16*)(ws + OFF_AF0);
  _Float16* AF1 = (_Float16*)(ws + OFF_AF1);
  _Float16* W1p = (_Float16*)(ws + OFF_W1);
  _Float16* W2p = (_Float16*)(ws + OFF_W2);
  float*    bs1 = (float*)(ws + OFF_B1);
  float*    bs2 = (float*)(ws + OFF_B2);

  // zero barrier + state buffers (h,c start at 0); zero out (atomic accumulation)
  hipMemsetAsync(ws, 0, (size_t)OFF_W1, stream);
  hipMemsetAsync(d_out, 0, (size_t)out_size * sizeof(float), stream);

  lstm_prep<<<2048, 256, 0, stream>>>(Whh1, Wih2, Whh2, bih1, bhh1, bih2, bhh2,
                                      W1p, W2p, bs1, bs2);
  lstm_main<<<512, 256, 0, stream>>>(x, Wih1, Wl, bl, AO0, AO1, AF0, AF1,
                                     W1p, W2p, bs1, bs2, bar, (float*)d_out);
}